// Round 1
// baseline (320.254 us; speedup 1.0000x reference)
//
#include <hip/hip_runtime.h>
#include <stdint.h>

#define B_ 2
#define S_ 2048
#define D_ 2048
#define NH 16
#define NKV 4
#define HD_ 128

typedef unsigned short u16;
typedef unsigned int u32;
typedef __attribute__((ext_vector_type(8))) __bf16 bf16x8;
typedef __attribute__((ext_vector_type(4))) float f32x4;
typedef __attribute__((ext_vector_type(8))) unsigned short ushort8v;
typedef __attribute__((ext_vector_type(4))) unsigned short ushort4v;

__device__ __forceinline__ u16 f2bf(float f) {
  u32 u = __builtin_bit_cast(u32, f);
  u32 r = (u + 0x7FFFu + ((u >> 16) & 1u)) >> 16;  // RNE
  return (u16)r;
}
__device__ __forceinline__ float bf2f(u16 h) {
  return __builtin_bit_cast(float, ((u32)h) << 16);
}

__device__ __forceinline__ void gld_lds16(const void* g, void* l) {
  __builtin_amdgcn_global_load_lds(
      (const __attribute__((address_space(1))) void*)g,
      (__attribute__((address_space(3))) void*)l, 16, 0, 0);
}

// ---------------- fp32 -> bf16 convert ----------------
__global__ __launch_bounds__(256) void k_f2b(const float* __restrict__ src,
                                             u16* __restrict__ dst, int n8) {
  int i = blockIdx.x * 256 + threadIdx.x;
  if (i >= n8) return;
  const float4* s = (const float4*)src + 2 * (size_t)i;
  float4 a = s[0], b = s[1];
  ushort8v o;
  o[0] = f2bf(a.x); o[1] = f2bf(a.y); o[2] = f2bf(a.z); o[3] = f2bf(a.w);
  o[4] = f2bf(b.x); o[5] = f2bf(b.y); o[6] = f2bf(b.z); o[7] = f2bf(b.w);
  *((ushort8v*)dst + i) = o;
}

// ---------------- GEMM: C[M,N] = A[M,K] * W[N,K]^T (bf16 in, fp32 acc) -------
// 128x128 tile, BK=64, 4 waves (2x2 of 64x64), 16x16x32 MFMA.
// LDS tiles XOR-swizzled: byte ^= ((row&7)<<4); staging pre-swizzles the
// GLOBAL source so global_load_lds (linear dest) lands swizzled (rule #21).
__device__ __forceinline__ void cstore(float* C, size_t i, float v) { C[i] = v; }
__device__ __forceinline__ void cstore(u16* C, size_t i, float v) { C[i] = f2bf(v); }

template <typename OT>
__device__ __forceinline__ void gemm_core(char* lds, const u16* __restrict__ A,
                                          const u16* __restrict__ W, OT* __restrict__ C,
                                          int N, int K, int bx, int by) {
  char* ldsA = lds;
  char* ldsB = lds + 16384;
  const int tid = threadIdx.x;
  const int lane = tid & 63;
  const int wave = tid >> 6;
  const int m0 = bx * 128, n0 = by * 128;
  const int wm = (wave >> 1) * 64, wn = (wave & 1) * 64;
  f32x4 acc[4][4];
#pragma unroll
  for (int i = 0; i < 4; ++i)
#pragma unroll
    for (int j = 0; j < 4; ++j) acc[i][j] = f32x4{0.f, 0.f, 0.f, 0.f};
  const size_t Kb2 = (size_t)K * 2;
  int rowS[4], colS[4];
#pragma unroll
  for (int j = 0; j < 4; ++j) {
    int plin = j * 4096 + tid * 16;
    int o = plin ^ (((plin >> 7) & 7) << 4);  // involution: sel bits 7-9 -> tgt 4-6
    rowS[j] = o >> 7;
    colS[j] = o & 127;
  }
  for (int kt = 0; kt < K; kt += 64) {
#pragma unroll
    for (int j = 0; j < 4; ++j) {
      gld_lds16((const char*)A + (size_t)(m0 + rowS[j]) * Kb2 + (size_t)kt * 2 + colS[j],
                ldsA + j * 4096 + wave * 1024);
      gld_lds16((const char*)W + (size_t)(n0 + rowS[j]) * Kb2 + (size_t)kt * 2 + colS[j],
                ldsB + j * 4096 + wave * 1024);
    }
    __syncthreads();
#pragma unroll
    for (int kk = 0; kk < 2; ++kk) {
      const int colb = kk * 64 + ((lane >> 4) << 4);
      bf16x8 af[4], bfv[4];
#pragma unroll
      for (int mi = 0; mi < 4; ++mi) {
        int row = wm + mi * 16 + (lane & 15);
        af[mi] = *(const bf16x8*)(ldsA + (row << 7) + (colb ^ ((row & 7) << 4)));
      }
#pragma unroll
      for (int ni = 0; ni < 4; ++ni) {
        int row = wn + ni * 16 + (lane & 15);
        bfv[ni] = *(const bf16x8*)(ldsB + (row << 7) + (colb ^ ((row & 7) << 4)));
      }
#pragma unroll
      for (int mi = 0; mi < 4; ++mi)
#pragma unroll
        for (int ni = 0; ni < 4; ++ni)
          acc[mi][ni] = __builtin_amdgcn_mfma_f32_16x16x32_bf16(af[mi], bfv[ni], acc[mi][ni], 0, 0, 0);
    }
    __syncthreads();
  }
#pragma unroll
  for (int mi = 0; mi < 4; ++mi)
#pragma unroll
    for (int ni = 0; ni < 4; ++ni) {
      const int n = n0 + wn + ni * 16 + (lane & 15);
#pragma unroll
      for (int r = 0; r < 4; ++r) {
        const int m = m0 + wm + mi * 16 + ((lane >> 4) << 2) + r;
        cstore(C, (size_t)m * N + n, acc[mi][ni][r]);
      }
    }
}

__global__ __launch_bounds__(256) void k_gemm_qkv(const u16* __restrict__ A,
    const u16* __restrict__ Wq, const u16* __restrict__ Wk, const u16* __restrict__ Wv,
    u16* __restrict__ q, u16* __restrict__ k, u16* __restrict__ v, int K) {
  __shared__ char lds[32768];
  const int z = blockIdx.z;
  if (z == 0) gemm_core(lds, A, Wq, q, 2048, K, blockIdx.x, blockIdx.y);
  else if (blockIdx.y < 4) {
    if (z == 1) gemm_core(lds, A, Wk, k, 512, K, blockIdx.x, blockIdx.y);
    else        gemm_core(lds, A, Wv, v, 512, K, blockIdx.x, blockIdx.y);
  }
}

__global__ __launch_bounds__(256) void k_gemm_out(const u16* __restrict__ A,
    const u16* __restrict__ W, float* __restrict__ C, int N, int K) {
  __shared__ char lds[32768];
  gemm_core(lds, A, W, C, N, K, blockIdx.x, blockIdx.y);
}

// ---------------- RoPE + relayout: [t, h*128+hd] -> [b][h][s][hd] bf16 ------
__global__ __launch_bounds__(256) void k_rope(const u16* __restrict__ src,
    u16* __restrict__ dst, const float* __restrict__ fc, const float* __restrict__ fs,
    int nh, int lognh, int dorope, int total) {
  int idx = blockIdx.x * 256 + threadIdx.x;
  if (idx >= total) return;
  const int q4 = idx & 15;           // quad of 4 pairs = 8 elems
  const int rest = idx >> 4;
  const int hidx = rest & (nh - 1);
  const int t = rest >> lognh;
  const int b = t >> 11, s = t & 2047;
  ushort8v ev = *(const ushort8v*)(src + (size_t)t * (nh * HD_) + hidx * HD_ + q4 * 8);
  float e[8];
#pragma unroll
  for (int j = 0; j < 8; ++j) e[j] = bf2f(ev[j]);
  float o[8];
  if (dorope) {
    float4 c4 = *(const float4*)(fc + s * 64 + q4 * 4);
    float4 s4 = *(const float4*)(fs + s * 64 + q4 * 4);
    float cc[4] = {c4.x, c4.y, c4.z, c4.w};
    float ss[4] = {s4.x, s4.y, s4.z, s4.w};
#pragma unroll
    for (int j = 0; j < 4; ++j) {
      o[2 * j]     = e[2 * j] * cc[j] - e[2 * j + 1] * ss[j];
      o[2 * j + 1] = e[2 * j] * ss[j] + e[2 * j + 1] * cc[j];
    }
  } else {
#pragma unroll
    for (int j = 0; j < 8; ++j) o[j] = e[j];
  }
  ushort8v w;
#pragma unroll
  for (int j = 0; j < 8; ++j) w[j] = f2bf(o[j]);
  *(ushort8v*)(dst + (((size_t)(b * nh + hidx)) * S_ + s) * HD_ + q4 * 8) = w;
}

// ---------------- causal GQA flash attention ----------------
// 256 thr = 4 waves; block = 64 q rows (16/wave); KBLK=64.
// Swapped QK^T: mfma(K,Q) -> S^T with col=q=lane&15 (softmax stats lane-local).
// P roundtrips through LDS to re-fragment for PV. V staged transposed ([hd][kv])
// via register pair-packing; all LDS tiles XOR-swizzled (conflict-free b128).
__global__ __launch_bounds__(256) void k_attn(const u16* __restrict__ Q,
    const u16* __restrict__ Kt, const u16* __restrict__ V, u16* __restrict__ O) {
  __shared__ char kls[16384];   // K tile [64][256B], swizzled
  __shared__ char vls[16384];   // V^T tile [128][128B], swizzled
  __shared__ char pls[8192];    // per-wave P [16][128B], swizzled
  const int qt = blockIdx.x, h = blockIdx.y, b = blockIdx.z;
  const int tid = threadIdx.x, lane = tid & 63, wave = tid >> 6;
  const int kvh = h >> 2;
  const u16* Qb = Q + ((size_t)(b * NH + h)) * S_ * HD_;
  const u16* Kb = Kt + ((size_t)(b * NKV + kvh)) * S_ * HD_;
  const u16* Vb = V + ((size_t)(b * NKV + kvh)) * S_ * HD_;
  const int q0 = qt * 64, qw0 = q0 + wave * 16;
  const int qme = lane & 15;
  bf16x8 qf[4];
#pragma unroll
  for (int kk = 0; kk < 4; ++kk)
    qf[kk] = *(const bf16x8*)(Qb + (size_t)(qw0 + qme) * HD_ + kk * 32 + ((lane >> 4) << 3));
  f32x4 oacc[8];
#pragma unroll
  for (int i = 0; i < 8; ++i) oacc[i] = f32x4{0.f, 0.f, 0.f, 0.f};
  float mrun = -1e30f, lrun = 0.0f;
  const float scale = 0.08838834764831845f;  // 1/sqrt(128)
  const int nt = qt + 1;
  char* pw = pls + wave * 2048;
  for (int t = 0; t < nt; ++t) {
    const int kv0 = t * 64;
    // stage K (global_load_lds, source pre-swizzled; 256B rows: sel bits 8-10)
#pragma unroll
    for (int j = 0; j < 4; ++j) {
      int plin = j * 4096 + tid * 16;
      int o = plin ^ (((plin >> 8) & 7) << 4);
      gld_lds16((const char*)Kb + (size_t)(kv0 + (o >> 8)) * 256 + (o & 255),
                kls + j * 4096 + wave * 1024);
    }
    // stage V^T: thread = (kv pair, 16-hd block); pack row pairs into dwords
    {
      const int kp = tid & 31, hb = (tid >> 5) * 16;
      const u16* vp = Vb + (size_t)(kv0 + 2 * kp) * HD_ + hb;
      const u32* r0 = (const u32*)vp;          // 8 dwords = hd hb..hb+15, row kv
      const u32* r1 = (const u32*)(vp + HD_);  // row kv+1
#pragma unroll
      for (int wd = 0; wd < 8; ++wd) {
        u32 v0 = r0[wd], v1 = r1[wd];
        u32 lo = (v0 & 0xFFFFu) | (v1 << 16);          // hd even: (kv, kv+1)
        u32 hi = (v0 >> 16) | (v1 & 0xFFFF0000u);      // hd odd
        int hd0 = hb + 2 * wd, hd1 = hd0 + 1;
        *(u32*)(vls + hd0 * 128 + ((4 * kp) ^ ((hd0 & 7) << 4))) = lo;
        *(u32*)(vls + hd1 * 128 + ((4 * kp) ^ ((hd1 & 7) << 4))) = hi;
      }
    }
    __syncthreads();
    // S^T = K * Q^T  (A=K rows kv, B=Q; C: col=q=lane&15, row=kv)
    f32x4 c[4];
#pragma unroll
    for (int nf = 0; nf < 4; ++nf) c[nf] = f32x4{0.f, 0.f, 0.f, 0.f};
#pragma unroll
    for (int kk = 0; kk < 4; ++kk) {
      const int colb = kk * 64 + ((lane >> 4) << 4);
#pragma unroll
      for (int nf = 0; nf < 4; ++nf) {
        int row = nf * 16 + qme;
        bf16x8 kf = *(const bf16x8*)(kls + (row << 8) + (colb ^ ((row & 7) << 4)));
        c[nf] = __builtin_amdgcn_mfma_f32_16x16x32_bf16(kf, qf[kk], c[nf], 0, 0, 0);
      }
    }
    // scale + causal mask (only diagonal tile) + online softmax (per q = lane&15)
    const bool last = (t == nt - 1);
    float mt = -1e30f;
#pragma unroll
    for (int nf = 0; nf < 4; ++nf)
#pragma unroll
      for (int r = 0; r < 4; ++r) {
        float s = c[nf][r] * scale;
        int kvi = kv0 + nf * 16 + ((lane >> 4) << 2) + r;
        if (last && kvi > qw0 + qme) s = -1e30f;
        c[nf][r] = s;
        mt = fmaxf(mt, s);
      }
    mt = fmaxf(mt, __shfl_xor(mt, 16));
    mt = fmaxf(mt, __shfl_xor(mt, 32));
    float mnew = fmaxf(mrun, mt);
    float alpha = __expf(mrun - mnew);
    float lt = 0.0f;
#pragma unroll
    for (int nf = 0; nf < 4; ++nf)
#pragma unroll
      for (int r = 0; r < 4; ++r) {
        float p = __expf(c[nf][r] - mnew);
        c[nf][r] = p;
        lt += p;
      }
    lt += __shfl_xor(lt, 16);
    lt += __shfl_xor(lt, 32);
    lrun = lrun * alpha + lt;
    mrun = mnew;
    // P -> LDS (row q = lane&15; kv packed 4 at a time)
#pragma unroll
    for (int nf = 0; nf < 4; ++nf) {
      ushort4v pv;
      pv[0] = f2bf(c[nf][0]); pv[1] = f2bf(c[nf][1]);
      pv[2] = f2bf(c[nf][2]); pv[3] = f2bf(c[nf][3]);
      int off = (qme << 7) + ((nf * 32 + ((lane >> 4) << 3)) ^ ((lane & 7) << 4));
      *(ushort4v*)(pw + off) = pv;
    }
    // rescale O (rows q=(lane>>4)*4+r need alpha from lane holding that q)
    float a4[4];
#pragma unroll
    for (int r = 0; r < 4; ++r)
      a4[r] = __shfl(alpha, (lane & 48) | (((lane >> 4) << 2) + r));
#pragma unroll
    for (int i = 0; i < 8; ++i)
#pragma unroll
      for (int r = 0; r < 4; ++r) oacc[i][r] *= a4[r];
    // PV: A = P[q][kv] from LDS, B = V^T frags; C rows=q, cols=hd
#pragma unroll
    for (int ks = 0; ks < 2; ++ks) {
      int poff = (qme << 7) + ((ks * 64 + ((lane >> 4) << 4)) ^ ((lane & 7) << 4));
      bf16x8 pf = *(const bf16x8*)(pw + poff);
#pragma unroll
      for (int nf = 0; nf < 8; ++nf) {
        int hd = nf * 16 + qme;
        int voff = (hd << 7) + ((ks * 64 + ((lane >> 4) << 4)) ^ ((hd & 7) << 4));
        bf16x8 vf = *(const bf16x8*)(vls + voff);
        oacc[nf] = __builtin_amdgcn_mfma_f32_16x16x32_bf16(pf, vf, oacc[nf], 0, 0, 0);
      }
    }
    __syncthreads();
  }
  float li[4];
#pragma unroll
  for (int r = 0; r < 4; ++r)
    li[r] = 1.0f / __shfl(lrun, (lane & 48) | (((lane >> 4) << 2) + r));
#pragma unroll
  for (int nf = 0; nf < 8; ++nf)
#pragma unroll
    for (int r = 0; r < 4; ++r) {
      int q = qw0 + ((lane >> 4) << 2) + r;
      int col = h * HD_ + nf * 16 + qme;
      O[(size_t)(b * S_ + q) * D_ + col] = f2bf(oacc[nf][r] * li[r]);
    }
}

// ---------------- launcher ----------------
// ws layout (60 MB total), with dead-buffer aliasing:
//  [ 0,16)MB xb            -> later Qb (bf16 [B,H,S,HD])
//  [16,24)MB wqb           -> later Kb[16,20) + Vb[20,24)
//  [24,26)MB wkb   [26,28)MB wvb   [28,36)MB wob
//  [36,52)MB qbf (GEMM out)-> later attb
//  [52,56)MB kbf   [56,60)MB vbf
extern "C" void kernel_launch(void* const* d_in, const int* in_sizes, int n_in,
                              void* d_out, int out_size, void* d_ws, size_t ws_size,
                              hipStream_t stream) {
  const float* x  = (const float*)d_in[0];
  const float* wq = (const float*)d_in[1];
  const float* wk = (const float*)d_in[2];
  const float* wv = (const float*)d_in[3];
  const float* wo = (const float*)d_in[4];
  const float* fc = (const float*)d_in[5];
  const float* fs = (const float*)d_in[6];
  float* out = (float*)d_out;
  char* ws = (char*)d_ws;
  const size_t MB = 1ull << 20;
  u16* xb   = (u16*)(ws);
  u16* wqb  = (u16*)(ws + 16 * MB);
  u16* wkb  = (u16*)(ws + 24 * MB);
  u16* wvb  = (u16*)(ws + 26 * MB);
  u16* wob  = (u16*)(ws + 28 * MB);
  u16* qbf  = (u16*)(ws + 36 * MB);
  u16* kbf  = (u16*)(ws + 52 * MB);
  u16* vbf  = (u16*)(ws + 56 * MB);
  u16* Qb   = (u16*)(ws);            // alias xb (dead after QKV GEMM)
  u16* Kb   = (u16*)(ws + 16 * MB);  // alias wqb (dead after QKV GEMM)
  u16* Vb   = (u16*)(ws + 20 * MB);
  u16* attb = (u16*)(ws + 36 * MB);  // alias qbf (dead after rope)

  auto cv = [&](const float* s, u16* d, int n) {
    int n8 = n / 8;
    k_f2b<<<dim3((n8 + 255) / 256), dim3(256), 0, stream>>>(s, d, n8);
  };
  cv(x,  xb,  B_ * S_ * D_);
  cv(wq, wqb, D_ * D_);
  cv(wk, wkb, 512 * D_);
  cv(wv, wvb, 512 * D_);
  cv(wo, wob, D_ * D_);

  k_gemm_qkv<<<dim3(32, 16, 3), dim3(256), 0, stream>>>(xb, wqb, wkb, wvb, qbf, kbf, vbf, D_);

  k_rope<<<dim3(4096), dim3(256), 0, stream>>>(qbf, Qb, fc, fs, 16, 4, 1, B_ * S_ * 16 * 16);
  k_rope<<<dim3(1024), dim3(256), 0, stream>>>(kbf, Kb, fc, fs, 4, 2, 1, B_ * S_ * 4 * 16);
  k_rope<<<dim3(1024), dim3(256), 0, stream>>>(vbf, Vb, fc, fs, 4, 2, 0, B_ * S_ * 4 * 16);

  k_attn<<<dim3(32, 16, 2), dim3(256), 0, stream>>>(Qb, Kb, Vb, attb);

  k_gemm_out<<<dim3(32, 16), dim3(256), 0, stream>>>(attb, wob, out, D_, D_);
}

// Round 2
// 258.934 us; speedup vs baseline: 1.2368x; 1.2368x over previous
//
#include <hip/hip_runtime.h>
#include <stdint.h>

#define B_ 2
#define S_ 2048
#define D_ 2048
#define NH 16
#define NKV 4
#define HD_ 128

typedef unsigned short u16;
typedef unsigned int u32;
typedef __attribute__((ext_vector_type(8))) __bf16 bf16x8;
typedef __attribute__((ext_vector_type(4))) float f32x4;
typedef __attribute__((ext_vector_type(16))) float f32x16;
typedef __attribute__((ext_vector_type(4))) unsigned int u32x4;
typedef __attribute__((ext_vector_type(8))) unsigned short ushort8v;

__device__ __forceinline__ u16 f2bf(float f) {
  u32 u = __builtin_bit_cast(u32, f);
  u32 r = (u + 0x7FFFu + ((u >> 16) & 1u)) >> 16;  // RNE
  return (u16)r;
}
__device__ __forceinline__ float bf2f(u16 h) {
  return __builtin_bit_cast(float, ((u32)h) << 16);
}
__device__ __forceinline__ u32 cvtpk(float lo, float hi) {
  u32 r;
  asm("v_cvt_pk_bf16_f32 %0, %1, %2" : "=v"(r) : "v"(lo), "v"(hi));
  return r;
}
__device__ __forceinline__ f32x16 zero16() {
  f32x16 v;
#pragma unroll
  for (int i = 0; i < 16; ++i) v[i] = 0.f;
  return v;
}

__device__ __forceinline__ void gld_lds16(const void* g, void* l) {
  __builtin_amdgcn_global_load_lds(
      (const __attribute__((address_space(1))) void*)g,
      (__attribute__((address_space(3))) void*)l, 16, 0, 0);
}

// ---------------- fp32 -> bf16 convert ----------------
__global__ __launch_bounds__(256) void k_f2b(const float* __restrict__ src,
                                             u16* __restrict__ dst, int n8) {
  int i = blockIdx.x * 256 + threadIdx.x;
  if (i >= n8) return;
  const float4* s = (const float4*)src + 2 * (size_t)i;
  float4 a = s[0], b = s[1];
  ushort8v o;
  o[0] = f2bf(a.x); o[1] = f2bf(a.y); o[2] = f2bf(a.z); o[3] = f2bf(a.w);
  o[4] = f2bf(b.x); o[5] = f2bf(b.y); o[6] = f2bf(b.z); o[7] = f2bf(b.w);
  *((ushort8v*)dst + i) = o;
}

// ---------------- GEMM: C[M,N] = A[M,K] * W[N,K]^T (bf16 in, fp32 acc) -------
__device__ __forceinline__ void cstore(float* C, size_t i, float v) { C[i] = v; }
__device__ __forceinline__ void cstore(u16* C, size_t i, float v) { C[i] = f2bf(v); }

template <typename OT>
__device__ __forceinline__ void gemm_core(char* lds, const u16* __restrict__ A,
                                          const u16* __restrict__ W, OT* __restrict__ C,
                                          int N, int K, int bx, int by) {
  char* ldsA = lds;
  char* ldsB = lds + 16384;
  const int tid = threadIdx.x;
  const int lane = tid & 63;
  const int wave = tid >> 6;
  const int m0 = bx * 128, n0 = by * 128;
  const int wm = (wave >> 1) * 64, wn = (wave & 1) * 64;
  f32x4 acc[4][4];
#pragma unroll
  for (int i = 0; i < 4; ++i)
#pragma unroll
    for (int j = 0; j < 4; ++j) acc[i][j] = f32x4{0.f, 0.f, 0.f, 0.f};
  const size_t Kb2 = (size_t)K * 2;
  int rowS[4], colS[4];
#pragma unroll
  for (int j = 0; j < 4; ++j) {
    int plin = j * 4096 + tid * 16;
    int o = plin ^ (((plin >> 7) & 7) << 4);
    rowS[j] = o >> 7;
    colS[j] = o & 127;
  }
  for (int kt = 0; kt < K; kt += 64) {
#pragma unroll
    for (int j = 0; j < 4; ++j) {
      gld_lds16((const char*)A + (size_t)(m0 + rowS[j]) * Kb2 + (size_t)kt * 2 + colS[j],
                ldsA + j * 4096 + wave * 1024);
      gld_lds16((const char*)W + (size_t)(n0 + rowS[j]) * Kb2 + (size_t)kt * 2 + colS[j],
                ldsB + j * 4096 + wave * 1024);
    }
    __syncthreads();
#pragma unroll
    for (int kk = 0; kk < 2; ++kk) {
      const int colb = kk * 64 + ((lane >> 4) << 4);
      bf16x8 af[4], bfv[4];
#pragma unroll
      for (int mi = 0; mi < 4; ++mi) {
        int row = wm + mi * 16 + (lane & 15);
        af[mi] = *(const bf16x8*)(ldsA + (row << 7) + (colb ^ ((row & 7) << 4)));
      }
#pragma unroll
      for (int ni = 0; ni < 4; ++ni) {
        int row = wn + ni * 16 + (lane & 15);
        bfv[ni] = *(const bf16x8*)(ldsB + (row << 7) + (colb ^ ((row & 7) << 4)));
      }
#pragma unroll
      for (int mi = 0; mi < 4; ++mi)
#pragma unroll
        for (int ni = 0; ni < 4; ++ni)
          acc[mi][ni] = __builtin_amdgcn_mfma_f32_16x16x32_bf16(af[mi], bfv[ni], acc[mi][ni], 0, 0, 0);
    }
    __syncthreads();
  }
#pragma unroll
  for (int mi = 0; mi < 4; ++mi)
#pragma unroll
    for (int ni = 0; ni < 4; ++ni) {
      const int n = n0 + wn + ni * 16 + (lane & 15);
#pragma unroll
      for (int r = 0; r < 4; ++r) {
        const int m = m0 + wm + mi * 16 + ((lane >> 4) << 2) + r;
        cstore(C, (size_t)m * N + n, acc[mi][ni][r]);
      }
    }
}

__global__ __launch_bounds__(256) void k_gemm_qkv(const u16* __restrict__ A,
    const u16* __restrict__ Wq, const u16* __restrict__ Wk, const u16* __restrict__ Wv,
    u16* __restrict__ q, u16* __restrict__ k, u16* __restrict__ v, int K) {
  __shared__ char lds[32768];
  const int z = blockIdx.z;
  if (z == 0) gemm_core(lds, A, Wq, q, 2048, K, blockIdx.x, blockIdx.y);
  else if (blockIdx.y < 4) {
    if (z == 1) gemm_core(lds, A, Wk, k, 512, K, blockIdx.x, blockIdx.y);
    else        gemm_core(lds, A, Wv, v, 512, K, blockIdx.x, blockIdx.y);
  }
}

__global__ __launch_bounds__(256) void k_gemm_out(const u16* __restrict__ A,
    const u16* __restrict__ W, float* __restrict__ C, int N, int K) {
  __shared__ char lds[32768];
  gemm_core(lds, A, W, C, N, K, blockIdx.x, blockIdx.y);
}

// ---------------- RoPE + relayout ----------------
__global__ __launch_bounds__(256) void k_rope(const u16* __restrict__ src,
    u16* __restrict__ dst, const float* __restrict__ fc, const float* __restrict__ fs,
    int nh, int lognh, int dorope, int total) {
  int idx = blockIdx.x * 256 + threadIdx.x;
  if (idx >= total) return;
  const int q4 = idx & 15;
  const int rest = idx >> 4;
  const int hidx = rest & (nh - 1);
  const int t = rest >> lognh;
  const int b = t >> 11, s = t & 2047;
  ushort8v ev = *(const ushort8v*)(src + (size_t)t * (nh * HD_) + hidx * HD_ + q4 * 8);
  float e[8];
#pragma unroll
  for (int j = 0; j < 8; ++j) e[j] = bf2f(ev[j]);
  float o[8];
  if (dorope) {
    float4 c4 = *(const float4*)(fc + s * 64 + q4 * 4);
    float4 s4 = *(const float4*)(fs + s * 64 + q4 * 4);
    float cc[4] = {c4.x, c4.y, c4.z, c4.w};
    float ss[4] = {s4.x, s4.y, s4.z, s4.w};
#pragma unroll
    for (int j = 0; j < 4; ++j) {
      o[2 * j]     = e[2 * j] * cc[j] - e[2 * j + 1] * ss[j];
      o[2 * j + 1] = e[2 * j] * ss[j] + e[2 * j + 1] * cc[j];
    }
  } else {
#pragma unroll
    for (int j = 0; j < 8; ++j) o[j] = e[j];
  }
  ushort8v w;
#pragma unroll
  for (int j = 0; j < 8; ++j) w[j] = f2bf(o[j]);
  *(ushort8v*)(dst + (((size_t)(b * nh + hidx)) * S_ + s) * HD_ + q4 * 8) = w;
}

// ---------------- causal GQA flash attention (32x32 MFMA, in-reg softmax) ----
__global__ __launch_bounds__(256, 2) void k_attn(const u16* __restrict__ Q,
    const u16* __restrict__ Kt, const u16* __restrict__ V, u16* __restrict__ O) {
  __shared__ char kls[16384];   // K tile [64][256B], XOR-swizzled
  __shared__ char vls[16384];   // V^T tile [128][128B], XOR-swizzled
  const int h = blockIdx.x, b = blockIdx.y;
  const int qtb = 15 - blockIdx.z;  // longest-first dispatch
  const int tid = threadIdx.x, lane = tid & 63, wave = tid >> 6;
  const int ql = lane & 31, g = lane >> 5;
  const int kvh = h >> 2;
  const u16* Qb = Q + ((size_t)(b * NH + h)) * S_ * HD_;
  const u16* Kb = Kt + ((size_t)(b * NKV + kvh)) * S_ * HD_;
  const u16* Vb = V + ((size_t)(b * NKV + kvh)) * S_ * HD_;
  const int q0 = qtb * 128, qw0 = q0 + wave * 32;
  const int qme = qw0 + ql;
  bf16x8 qf[8];
#pragma unroll
  for (int kk = 0; kk < 8; ++kk)
    qf[kk] = *(const bf16x8*)(Qb + (size_t)qme * HD_ + kk * 16 + g * 8);
  f32x16 oacc[4];
#pragma unroll
  for (int th = 0; th < 4; ++th) oacc[th] = zero16();
  float mrun = -1e30f, lrun = 0.0f;
  const float scale = 0.08838834764831845f;  // 1/sqrt(128)
  const int nt = 2 * qtb + 2;
  for (int t = 0; t < nt; ++t) {
    const int kv0 = t * 64;
#pragma unroll
    for (int j = 0; j < 4; ++j) {
      int plin = j * 4096 + tid * 16;
      int o = plin ^ (((plin >> 8) & 7) << 4);
      gld_lds16((const char*)Kb + (size_t)(kv0 + (o >> 8)) * 256 + (o & 255),
                kls + j * 4096 + wave * 1024);
    }
    {
      const int kp = tid & 31, hb = (tid >> 5) * 16;
      const u16* vp = Vb + (size_t)(kv0 + 2 * kp) * HD_ + hb;
      const u32* r0 = (const u32*)vp;
      const u32* r1 = (const u32*)(vp + HD_);
#pragma unroll
      for (int wd = 0; wd < 8; ++wd) {
        u32 v0 = r0[wd], v1 = r1[wd];
        u32 lo = (v0 & 0xFFFFu) | (v1 << 16);
        u32 hi = (v0 >> 16) | (v1 & 0xFFFF0000u);
        int hd0 = hb + 2 * wd, hd1 = hd0 + 1;
        *(u32*)(vls + hd0 * 128 + ((4 * kp) ^ ((hd0 & 7) << 4))) = lo;
        *(u32*)(vls + hd1 * 128 + ((4 * kp) ^ ((hd1 & 7) << 4))) = hi;
      }
    }
    __syncthreads();
    if (kv0 <= qw0 + 31) {
      f32x16 c0 = zero16(), c1 = zero16();
      __builtin_amdgcn_s_setprio(1);
#pragma unroll
      for (int kk = 0; kk < 8; ++kk) {
        const int sw = (kk * 32 + 16 * g) ^ ((ql & 7) << 4);
        bf16x8 kf0 = *(const bf16x8*)(kls + (ql << 8) + sw);
        bf16x8 kf1 = *(const bf16x8*)(kls + ((32 + ql) << 8) + sw);
        c0 = __builtin_amdgcn_mfma_f32_32x32x16_bf16(kf0, qf[kk], c0, 0, 0, 0);
        c1 = __builtin_amdgcn_mfma_f32_32x32x16_bf16(kf1, qf[kk], c1, 0, 0, 0);
      }
      __builtin_amdgcn_s_setprio(0);
      const bool diag = (kv0 + 63 > qw0);
      float mt = -1e30f;
#pragma unroll
      for (int r = 0; r < 16; ++r) {
        float s0 = c0[r] * scale;
        float s1 = c1[r] * scale;
        if (diag) {
          int kb = kv0 + (r & 3) + ((r >> 2) << 3) + 4 * g;
          if (kb > qme) s0 = -1e30f;
          if (kb + 32 > qme) s1 = -1e30f;
        }
        c0[r] = s0; c1[r] = s1;
        mt = fmaxf(mt, fmaxf(s0, s1));
      }
      mt = fmaxf(mt, __shfl_xor(mt, 32));
      if (!__all(mt <= mrun + 8.0f)) {
        float mnew = fmaxf(mrun, mt);
        float alpha = __expf(mrun - mnew);
        lrun *= alpha;
        mrun = mnew;
#pragma unroll
        for (int r = 0; r < 16; ++r) {
          float av = __shfl(alpha, 36 * g + (r & 3) + ((r >> 2) << 3));
          oacc[0][r] *= av; oacc[1][r] *= av;
          oacc[2][r] *= av; oacc[3][r] *= av;
        }
      }
      float lt = 0.0f;
#pragma unroll
      for (int r = 0; r < 16; ++r) {
        float p0 = __expf(c0[r] - mrun);
        float p1 = __expf(c1[r] - mrun);
        c0[r] = p0; c1[r] = p1;
        lt += p0 + p1;
      }
      lt += __shfl_xor(lt, 32);
      lrun += lt;
      u32 paw[4][4];
#pragma unroll
      for (int a = 0; a < 2; ++a) {
        {
          u32 X = cvtpk(c0[8 * a + 0], c0[8 * a + 1]);
          u32 Y = cvtpk(c0[8 * a + 2], c0[8 * a + 3]);
          u32 Z = cvtpk(c0[8 * a + 4], c0[8 * a + 5]);
          u32 W = cvtpk(c0[8 * a + 6], c0[8 * a + 7]);
          u32 S1 = g ? X : Z, S2 = g ? Y : W;
          u32 R1 = (u32)__shfl_xor((int)S1, 32), R2 = (u32)__shfl_xor((int)S2, 32);
          paw[a][0] = g ? R1 : X; paw[a][1] = g ? R2 : Y;
          paw[a][2] = g ? Z : R1; paw[a][3] = g ? W : R2;
        }
        {
          u32 X = cvtpk(c1[8 * a + 0], c1[8 * a + 1]);
          u32 Y = cvtpk(c1[8 * a + 2], c1[8 * a + 3]);
          u32 Z = cvtpk(c1[8 * a + 4], c1[8 * a + 5]);
          u32 W = cvtpk(c1[8 * a + 6], c1[8 * a + 7]);
          u32 S1 = g ? X : Z, S2 = g ? Y : W;
          u32 R1 = (u32)__shfl_xor((int)S1, 32), R2 = (u32)__shfl_xor((int)S2, 32);
          paw[2 + a][0] = g ? R1 : X; paw[2 + a][1] = g ? R2 : Y;
          paw[2 + a][2] = g ? Z : R1; paw[2 + a][3] = g ? W : R2;
        }
      }
      __builtin_amdgcn_s_setprio(1);
#pragma unroll
      for (int ks = 0; ks < 4; ++ks) {
        bf16x8 pf = __builtin_bit_cast(bf16x8,
            u32x4{paw[ks][0], paw[ks][1], paw[ks][2], paw[ks][3]});
        const int cb = (32 * ks + 16 * g) ^ ((ql & 7) << 4);
#pragma unroll
        for (int th = 0; th < 4; ++th) {
          bf16x8 vf = *(const bf16x8*)(vls + ((th * 32 + ql) << 7) + cb);
          oacc[th] = __builtin_amdgcn_mfma_f32_32x32x16_bf16(pf, vf, oacc[th], 0, 0, 0);
        }
      }
      __builtin_amdgcn_s_setprio(0);
    }
    __syncthreads();
  }
#pragma unroll
  for (int r = 0; r < 16; ++r) {
    float lr = __shfl(lrun, 36 * g + (r & 3) + ((r >> 2) << 3));
    float li = 1.0f / lr;
    int q = qw0 + (r & 3) + ((r >> 2) << 3) + 4 * g;
    size_t rowo = (size_t)(b * S_ + q) * D_ + h * HD_ + ql;
#pragma unroll
    for (int th = 0; th < 4; ++th)
      O[rowo + 32 * th] = f2bf(oacc[th][r] * li);
  }
}

// ---------------- launcher ----------------
extern "C" void kernel_launch(void* const* d_in, const int* in_sizes, int n_in,
                              void* d_out, int out_size, void* d_ws, size_t ws_size,
                              hipStream_t stream) {
  const float* x  = (const float*)d_in[0];
  const float* wq = (const float*)d_in[1];
  const float* wk = (const float*)d_in[2];
  const float* wv = (const float*)d_in[3];
  const float* wo = (const float*)d_in[4];
  const float* fc = (const float*)d_in[5];
  const float* fs = (const float*)d_in[6];
  float* out = (float*)d_out;
  char* ws = (char*)d_ws;
  const size_t MB = 1ull << 20;
  u16* xb   = (u16*)(ws);
  u16* wqb  = (u16*)(ws + 16 * MB);
  u16* wkb  = (u16*)(ws + 24 * MB);
  u16* wvb  = (u16*)(ws + 26 * MB);
  u16* wob  = (u16*)(ws + 28 * MB);
  u16* qbf  = (u16*)(ws + 36 * MB);
  u16* kbf  = (u16*)(ws + 52 * MB);
  u16* vbf  = (u16*)(ws + 56 * MB);
  u16* Qb   = (u16*)(ws);            // alias xb (dead after QKV GEMM)
  u16* Kb   = (u16*)(ws + 16 * MB);  // alias wqb
  u16* Vb   = (u16*)(ws + 20 * MB);
  u16* attb = (u16*)(ws + 36 * MB);  // alias qbf (dead after rope)

  auto cv = [&](const float* s, u16* d, int n) {
    int n8 = n / 8;
    k_f2b<<<dim3((n8 + 255) / 256), dim3(256), 0, stream>>>(s, d, n8);
  };
  cv(x,  xb,  B_ * S_ * D_);
  cv(wq, wqb, D_ * D_);
  cv(wk, wkb, 512 * D_);
  cv(wv, wvb, 512 * D_);
  cv(wo, wob, D_ * D_);

  k_gemm_qkv<<<dim3(32, 16, 3), dim3(256), 0, stream>>>(xb, wqb, wkb, wvb, qbf, kbf, vbf, D_);

  k_rope<<<dim3(4096), dim3(256), 0, stream>>>(qbf, Qb, fc, fs, 16, 4, 1, B_ * S_ * 16 * 16);
  k_rope<<<dim3(1024), dim3(256), 0, stream>>>(kbf, Kb, fc, fs, 4, 2, 1, B_ * S_ * 4 * 16);
  k_rope<<<dim3(1024), dim3(256), 0, stream>>>(vbf, Vb, fc, fs, 4, 2, 0, B_ * S_ * 4 * 16);

  k_attn<<<dim3(NH, B_, 16), dim3(256), 0, stream>>>(Qb, Kb, Vb, attb);

  k_gemm_out<<<dim3(32, 16), dim3(256), 0, stream>>>(attb, wob, out, D_, D_);
}

// Round 3
// 252.798 us; speedup vs baseline: 1.2668x; 1.0243x over previous
//
#include <hip/hip_runtime.h>
#include <stdint.h>

#define B_ 2
#define S_ 2048
#define D_ 2048
#define NH 16
#define NKV 4
#define HD_ 128

typedef unsigned short u16;
typedef unsigned int u32;
typedef __attribute__((ext_vector_type(8))) __bf16 bf16x8;
typedef __attribute__((ext_vector_type(4))) float f32x4;
typedef __attribute__((ext_vector_type(16))) float f32x16;
typedef __attribute__((ext_vector_type(4))) unsigned int u32x4;
typedef __attribute__((ext_vector_type(8))) unsigned short ushort8v;

__device__ __forceinline__ u16 f2bf(float f) {
  u32 u = __builtin_bit_cast(u32, f);
  u32 r = (u + 0x7FFFu + ((u >> 16) & 1u)) >> 16;  // RNE
  return (u16)r;
}
__device__ __forceinline__ float bf2f(u16 h) {
  return __builtin_bit_cast(float, ((u32)h) << 16);
}
__device__ __forceinline__ u32 cvtpk(float lo, float hi) {
  u32 r;
  asm("v_cvt_pk_bf16_f32 %0, %1, %2" : "=v"(r) : "v"(lo), "v"(hi));
  return r;
}
__device__ __forceinline__ f32x16 zero16() {
  f32x16 v;
#pragma unroll
  for (int i = 0; i < 16; ++i) v[i] = 0.f;
  return v;
}

__device__ __forceinline__ void gld_lds16(const void* g, void* l) {
  __builtin_amdgcn_global_load_lds(
      (const __attribute__((address_space(1))) void*)g,
      (__attribute__((address_space(3))) void*)l, 16, 0, 0);
}

// ---------------- fp32 -> bf16 convert ----------------
__global__ __launch_bounds__(256) void k_f2b(const float* __restrict__ src,
                                             u16* __restrict__ dst, int n8) {
  int i = blockIdx.x * 256 + threadIdx.x;
  if (i >= n8) return;
  const float4* s = (const float4*)src + 2 * (size_t)i;
  float4 a = s[0], b = s[1];
  ushort8v o;
  o[0] = f2bf(a.x); o[1] = f2bf(a.y); o[2] = f2bf(a.z); o[3] = f2bf(a.w);
  o[4] = f2bf(b.x); o[5] = f2bf(b.y); o[6] = f2bf(b.z); o[7] = f2bf(b.w);
  *((ushort8v*)dst + i) = o;
}

// ---------------- GEMM: C[M,N] = A[M,K] * W[N,K]^T (bf16 in, fp32 acc) -------
__device__ __forceinline__ void cstore(float* C, size_t i, float v) { C[i] = v; }
__device__ __forceinline__ void cstore(u16* C, size_t i, float v) { C[i] = f2bf(v); }

template <typename OT>
__device__ __forceinline__ void gemm_core(char* lds, const u16* __restrict__ A,
                                          const u16* __restrict__ W, OT* __restrict__ C,
                                          int N, int K, int bx, int by) {
  char* ldsA = lds;
  char* ldsB = lds + 16384;
  const int tid = threadIdx.x;
  const int lane = tid & 63;
  const int wave = tid >> 6;
  const int m0 = bx * 128, n0 = by * 128;
  const int wm = (wave >> 1) * 64, wn = (wave & 1) * 64;
  f32x4 acc[4][4];
#pragma unroll
  for (int i = 0; i < 4; ++i)
#pragma unroll
    for (int j = 0; j < 4; ++j) acc[i][j] = f32x4{0.f, 0.f, 0.f, 0.f};
  const size_t Kb2 = (size_t)K * 2;
  int rowS[4], colS[4];
#pragma unroll
  for (int j = 0; j < 4; ++j) {
    int plin = j * 4096 + tid * 16;
    int o = plin ^ (((plin >> 7) & 7) << 4);
    rowS[j] = o >> 7;
    colS[j] = o & 127;
  }
  for (int kt = 0; kt < K; kt += 64) {
#pragma unroll
    for (int j = 0; j < 4; ++j) {
      gld_lds16((const char*)A + (size_t)(m0 + rowS[j]) * Kb2 + (size_t)kt * 2 + colS[j],
                ldsA + j * 4096 + wave * 1024);
      gld_lds16((const char*)W + (size_t)(n0 + rowS[j]) * Kb2 + (size_t)kt * 2 + colS[j],
                ldsB + j * 4096 + wave * 1024);
    }
    __syncthreads();
#pragma unroll
    for (int kk = 0; kk < 2; ++kk) {
      const int colb = kk * 64 + ((lane >> 4) << 4);
      bf16x8 af[4], bfv[4];
#pragma unroll
      for (int mi = 0; mi < 4; ++mi) {
        int row = wm + mi * 16 + (lane & 15);
        af[mi] = *(const bf16x8*)(ldsA + (row << 7) + (colb ^ ((row & 7) << 4)));
      }
#pragma unroll
      for (int ni = 0; ni < 4; ++ni) {
        int row = wn + ni * 16 + (lane & 15);
        bfv[ni] = *(const bf16x8*)(ldsB + (row << 7) + (colb ^ ((row & 7) << 4)));
      }
#pragma unroll
      for (int mi = 0; mi < 4; ++mi)
#pragma unroll
        for (int ni = 0; ni < 4; ++ni)
          acc[mi][ni] = __builtin_amdgcn_mfma_f32_16x16x32_bf16(af[mi], bfv[ni], acc[mi][ni], 0, 0, 0);
    }
    __syncthreads();
  }
#pragma unroll
  for (int mi = 0; mi < 4; ++mi)
#pragma unroll
    for (int ni = 0; ni < 4; ++ni) {
      const int n = n0 + wn + ni * 16 + (lane & 15);
#pragma unroll
      for (int r = 0; r < 4; ++r) {
        const int m = m0 + wm + mi * 16 + ((lane >> 4) << 2) + r;
        cstore(C, (size_t)m * N + n, acc[mi][ni][r]);
      }
    }
}

__global__ __launch_bounds__(256) void k_gemm_bf(const u16* __restrict__ A,
    const u16* __restrict__ W, u16* __restrict__ C, int N, int K) {
  __shared__ char lds[32768];
  gemm_core(lds, A, W, C, N, K, blockIdx.x, blockIdx.y);
}

__global__ __launch_bounds__(256) void k_gemm_out(const u16* __restrict__ A,
    const u16* __restrict__ W, float* __restrict__ C, int N, int K) {
  __shared__ char lds[32768];
  gemm_core(lds, A, W, C, N, K, blockIdx.x, blockIdx.y);
}

// ---------------- RoPE + relayout: fused-QKV src (row stride rs) ------------
__global__ __launch_bounds__(256) void k_rope(const u16* __restrict__ src,
    u16* __restrict__ dst, const float* __restrict__ fc, const float* __restrict__ fs,
    int nh, int lognh, int dorope, int total, int rs, int coloff) {
  int idx = blockIdx.x * 256 + threadIdx.x;
  if (idx >= total) return;
  const int q4 = idx & 15;
  const int rest = idx >> 4;
  const int hidx = rest & (nh - 1);
  const int t = rest >> lognh;
  const int b = t >> 11, s = t & 2047;
  ushort8v ev = *(const ushort8v*)(src + (size_t)t * rs + coloff + hidx * HD_ + q4 * 8);
  float e[8];
#pragma unroll
  for (int j = 0; j < 8; ++j) e[j] = bf2f(ev[j]);
  float o[8];
  if (dorope) {
    float4 c4 = *(const float4*)(fc + s * 64 + q4 * 4);
    float4 s4 = *(const float4*)(fs + s * 64 + q4 * 4);
    float cc[4] = {c4.x, c4.y, c4.z, c4.w};
    float ss[4] = {s4.x, s4.y, s4.z, s4.w};
#pragma unroll
    for (int j = 0; j < 4; ++j) {
      o[2 * j]     = e[2 * j] * cc[j] - e[2 * j + 1] * ss[j];
      o[2 * j + 1] = e[2 * j] * ss[j] + e[2 * j + 1] * cc[j];
    }
  } else {
#pragma unroll
    for (int j = 0; j < 8; ++j) o[j] = e[j];
  }
  ushort8v w;
#pragma unroll
  for (int j = 0; j < 8; ++j) w[j] = f2bf(o[j]);
  *(ushort8v*)(dst + (((size_t)(b * nh + hidx)) * S_ + s) * HD_ + q4 * 8) = w;
}

// ---------------- causal GQA flash attention (dbuf + prefetch) --------------
// 4 waves x 32 q rows; KVBLK=64; swapped QK^T, in-reg softmax (cvt_pk+shfl),
// defer-max. Double-buffered K/V LDS: issue next-tile K gld_lds + V global
// loads BEFORE compute; pack+ds_write V after compute; ONE barrier per iter.
__global__ __launch_bounds__(256, 2) void k_attn(const u16* __restrict__ Q,
    const u16* __restrict__ Kt, const u16* __restrict__ V, u16* __restrict__ O) {
  __shared__ char kls[2][16384];   // K tile [64][256B], XOR-swizzled
  __shared__ char vls[2][16384];   // V^T tile [128 hd][128B kv], XOR-swizzled
  const int h = blockIdx.x, b = blockIdx.y;
  const int qtb = 15 - blockIdx.z;  // longest-first dispatch
  const int tid = threadIdx.x, lane = tid & 63, wave = tid >> 6;
  const int ql = lane & 31, g = lane >> 5;
  const int kvh = h >> 2;
  const u16* Qb = Q + ((size_t)(b * NH + h)) * S_ * HD_;
  const u16* Kb = Kt + ((size_t)(b * NKV + kvh)) * S_ * HD_;
  const u16* Vb = V + ((size_t)(b * NKV + kvh)) * S_ * HD_;
  const int q0 = qtb * 128, qw0 = q0 + wave * 32;
  const int qme = qw0 + ql;
  // staging constants
  int kRowS[4], kColS[4];
#pragma unroll
  for (int j = 0; j < 4; ++j) {
    int plin = j * 4096 + tid * 16;
    int o = plin ^ (((plin >> 8) & 7) << 4);
    kRowS[j] = o >> 8;
    kColS[j] = o & 255;
  }
  const int kp = tid & 31, hb = (tid >> 5) * 16;
  bf16x8 qf[8];
#pragma unroll
  for (int kk = 0; kk < 8; ++kk)
    qf[kk] = *(const bf16x8*)(Qb + (size_t)qme * HD_ + kk * 16 + g * 8);
  f32x16 oacc[4];
#pragma unroll
  for (int th = 0; th < 4; ++th) oacc[th] = zero16();
  float mrun = -1e30f, lrun = 0.0f;
  const float scale = 0.08838834764831845f;  // 1/sqrt(128)
  const int nt = 2 * qtb + 2;

  // ---- prologue: fully stage tile 0 ----
#pragma unroll
  for (int j = 0; j < 4; ++j)
    gld_lds16((const char*)Kb + (size_t)kRowS[j] * 256 + kColS[j],
              &kls[0][0] + j * 4096 + wave * 1024);
  {
    const u16* vp = Vb + (size_t)(2 * kp) * HD_ + hb;
    const u32* r0 = (const u32*)vp;
    const u32* r1 = (const u32*)(vp + HD_);
#pragma unroll
    for (int wd = 0; wd < 8; ++wd) {
      u32 v0 = r0[wd], v1 = r1[wd];
      u32 lo = (v0 & 0xFFFFu) | (v1 << 16);
      u32 hi = (v0 >> 16) | (v1 & 0xFFFF0000u);
      int hd0 = hb + 2 * wd, hd1 = hd0 + 1;
      *(u32*)(&vls[0][0] + hd0 * 128 + ((4 * kp) ^ ((hd0 & 7) << 4))) = lo;
      *(u32*)(&vls[0][0] + hd1 * 128 + ((4 * kp) ^ ((hd1 & 7) << 4))) = hi;
    }
  }
  __syncthreads();

  int cur = 0;
  for (int t = 0; t < nt; ++t) {
    const int kv0 = t * 64;
    const bool haveNext = (t + 1 < nt);
    u32 vr0[8], vr1[8];
    if (haveNext) {
      const int kvn = kv0 + 64;
      // issue K(t+1) -> LDS[nxt]
#pragma unroll
      for (int j = 0; j < 4; ++j)
        gld_lds16((const char*)Kb + (size_t)(kvn + kRowS[j]) * 256 + kColS[j],
                  &kls[cur ^ 1][0] + j * 4096 + wave * 1024);
      // issue V(t+1) -> regs
      const u16* vp = Vb + (size_t)(kvn + 2 * kp) * HD_ + hb;
      const u32* r0 = (const u32*)vp;
      const u32* r1 = (const u32*)(vp + HD_);
#pragma unroll
      for (int wd = 0; wd < 8; ++wd) { vr0[wd] = r0[wd]; vr1[wd] = r1[wd]; }
    }
    // ---- compute on buffer `cur` ----
    if (kv0 <= qw0 + 31) {
      const char* kcur = &kls[cur][0];
      const char* vcur = &vls[cur][0];
      f32x16 c0 = zero16(), c1 = zero16();
      __builtin_amdgcn_s_setprio(1);
#pragma unroll
      for (int kk = 0; kk < 8; ++kk) {
        const int sw = (kk * 32 + 16 * g) ^ ((ql & 7) << 4);
        bf16x8 kf0 = *(const bf16x8*)(kcur + (ql << 8) + sw);
        bf16x8 kf1 = *(const bf16x8*)(kcur + ((32 + ql) << 8) + sw);
        c0 = __builtin_amdgcn_mfma_f32_32x32x16_bf16(kf0, qf[kk], c0, 0, 0, 0);
        c1 = __builtin_amdgcn_mfma_f32_32x32x16_bf16(kf1, qf[kk], c1, 0, 0, 0);
      }
      __builtin_amdgcn_s_setprio(0);
      const bool diag = (kv0 + 63 > qw0);
      float mt = -1e30f;
#pragma unroll
      for (int r = 0; r < 16; ++r) {
        float s0 = c0[r] * scale;
        float s1 = c1[r] * scale;
        if (diag) {
          int kb = kv0 + (r & 3) + ((r >> 2) << 3) + 4 * g;
          if (kb > qme) s0 = -1e30f;
          if (kb + 32 > qme) s1 = -1e30f;
        }
        c0[r] = s0; c1[r] = s1;
        mt = fmaxf(mt, fmaxf(s0, s1));
      }
      mt = fmaxf(mt, __shfl_xor(mt, 32));
      if (!__all(mt <= mrun + 8.0f)) {
        float mnew = fmaxf(mrun, mt);
        float alpha = __expf(mrun - mnew);
        lrun *= alpha;
        mrun = mnew;
#pragma unroll
        for (int r = 0; r < 16; ++r) {
          float av = __shfl(alpha, 36 * g + (r & 3) + ((r >> 2) << 3));
          oacc[0][r] *= av; oacc[1][r] *= av;
          oacc[2][r] *= av; oacc[3][r] *= av;
        }
      }
      float lt = 0.0f;
#pragma unroll
      for (int r = 0; r < 16; ++r) {
        float p0 = __expf(c0[r] - mrun);
        float p1 = __expf(c1[r] - mrun);
        c0[r] = p0; c1[r] = p1;
        lt += p0 + p1;
      }
      lt += __shfl_xor(lt, 32);
      lrun += lt;
      u32 paw[4][4];
#pragma unroll
      for (int a = 0; a < 2; ++a) {
        {
          u32 X = cvtpk(c0[8 * a + 0], c0[8 * a + 1]);
          u32 Y = cvtpk(c0[8 * a + 2], c0[8 * a + 3]);
          u32 Z = cvtpk(c0[8 * a + 4], c0[8 * a + 5]);
          u32 W = cvtpk(c0[8 * a + 6], c0[8 * a + 7]);
          u32 S1 = g ? X : Z, S2 = g ? Y : W;
          u32 R1 = (u32)__shfl_xor((int)S1, 32), R2 = (u32)__shfl_xor((int)S2, 32);
          paw[a][0] = g ? R1 : X; paw[a][1] = g ? R2 : Y;
          paw[a][2] = g ? Z : R1; paw[a][3] = g ? W : R2;
        }
        {
          u32 X = cvtpk(c1[8 * a + 0], c1[8 * a + 1]);
          u32 Y = cvtpk(c1[8 * a + 2], c1[8 * a + 3]);
          u32 Z = cvtpk(c1[8 * a + 4], c1[8 * a + 5]);
          u32 W = cvtpk(c1[8 * a + 6], c1[8 * a + 7]);
          u32 S1 = g ? X : Z, S2 = g ? Y : W;
          u32 R1 = (u32)__shfl_xor((int)S1, 32), R2 = (u32)__shfl_xor((int)S2, 32);
          paw[2 + a][0] = g ? R1 : X; paw[2 + a][1] = g ? R2 : Y;
          paw[2 + a][2] = g ? Z : R1; paw[2 + a][3] = g ? W : R2;
        }
      }
      __builtin_amdgcn_s_setprio(1);
#pragma unroll
      for (int ks = 0; ks < 4; ++ks) {
        bf16x8 pf = __builtin_bit_cast(bf16x8,
            u32x4{paw[ks][0], paw[ks][1], paw[ks][2], paw[ks][3]});
        const int cb = (32 * ks + 16 * g) ^ ((ql & 7) << 4);
#pragma unroll
        for (int th = 0; th < 4; ++th) {
          bf16x8 vf = *(const bf16x8*)(vcur + ((th * 32 + ql) << 7) + cb);
          oacc[th] = __builtin_amdgcn_mfma_f32_32x32x16_bf16(pf, vf, oacc[th], 0, 0, 0);
        }
      }
      __builtin_amdgcn_s_setprio(0);
    }
    // ---- finish V(t+1) staging: pack regs -> LDS[nxt] ----
    if (haveNext) {
      char* vn = &vls[cur ^ 1][0];
#pragma unroll
      for (int wd = 0; wd < 8; ++wd) {
        u32 v0 = vr0[wd], v1 = vr1[wd];
        u32 lo = (v0 & 0xFFFFu) | (v1 << 16);
        u32 hi = (v0 >> 16) | (v1 & 0xFFFF0000u);
        int hd0 = hb + 2 * wd, hd1 = hd0 + 1;
        *(u32*)(vn + hd0 * 128 + ((4 * kp) ^ ((hd0 & 7) << 4))) = lo;
        *(u32*)(vn + hd1 * 128 + ((4 * kp) ^ ((hd1 & 7) << 4))) = hi;
      }
    }
    __syncthreads();
    cur ^= 1;
  }
#pragma unroll
  for (int r = 0; r < 16; ++r) {
    float lr = __shfl(lrun, 36 * g + (r & 3) + ((r >> 2) << 3));
    float li = 1.0f / lr;
    int q = qw0 + (r & 3) + ((r >> 2) << 3) + 4 * g;
    size_t rowo = (size_t)(b * S_ + q) * D_ + h * HD_ + ql;
#pragma unroll
    for (int th = 0; th < 4; ++th)
      O[rowo + 32 * th] = f2bf(oacc[th][r] * li);
  }
}

// ---------------- launcher ----------------
// ws layout (60 MB), aliasing:
//  [ 0,16) xb  -> Qb          [16,28) wqkv -> Kb[16,20)+Vb[20,24)
//  [28,36) wob                [36,60) qkvbf [4096][3072] -> attb[36,52)
extern "C" void kernel_launch(void* const* d_in, const int* in_sizes, int n_in,
                              void* d_out, int out_size, void* d_ws, size_t ws_size,
                              hipStream_t stream) {
  const float* x  = (const float*)d_in[0];
  const float* wq = (const float*)d_in[1];
  const float* wk = (const float*)d_in[2];
  const float* wv = (const float*)d_in[3];
  const float* wo = (const float*)d_in[4];
  const float* fc = (const float*)d_in[5];
  const float* fs = (const float*)d_in[6];
  float* out = (float*)d_out;
  char* ws = (char*)d_ws;
  const size_t MB = 1ull << 20;
  u16* xb    = (u16*)(ws);
  u16* wqkv  = (u16*)(ws + 16 * MB);           // [3072][2048] fused q|k|v
  u16* wob   = (u16*)(ws + 28 * MB);
  u16* qkvbf = (u16*)(ws + 36 * MB);           // [4096][3072]
  u16* Qb    = (u16*)(ws);                     // alias xb
  u16* Kb    = (u16*)(ws + 16 * MB);           // alias wqkv
  u16* Vb    = (u16*)(ws + 20 * MB);
  u16* attb  = (u16*)(ws + 36 * MB);           // alias qkvbf

  auto cv = [&](const float* s, u16* d, int n) {
    int n8 = n / 8;
    k_f2b<<<dim3((n8 + 255) / 256), dim3(256), 0, stream>>>(s, d, n8);
  };
  cv(x,  xb,   B_ * S_ * D_);
  cv(wq, wqkv,            D_ * D_);
  cv(wk, wqkv + 2048*2048, 512 * D_);
  cv(wv, wqkv + 2560*2048, 512 * D_);
  cv(wo, wob,  D_ * D_);

  k_gemm_bf<<<dim3(32, 24), dim3(256), 0, stream>>>(xb, wqkv, qkvbf, 3072, D_);

  k_rope<<<dim3(4096), dim3(256), 0, stream>>>(qkvbf, Qb, fc, fs, 16, 4, 1,
                                               B_ * S_ * 16 * 16, 3072, 0);
  k_rope<<<dim3(1024), dim3(256), 0, stream>>>(qkvbf, Kb, fc, fs, 4, 2, 1,
                                               B_ * S_ * 4 * 16, 3072, 2048);
  k_rope<<<dim3(1024), dim3(256), 0, stream>>>(qkvbf, Vb, fc, fs, 4, 2, 0,
                                               B_ * S_ * 4 * 16, 3072, 2560);

  k_attn<<<dim3(NH, B_, 16), dim3(256), 0, stream>>>(Qb, Kb, Vb, attb);

  k_gemm_out<<<dim3(32, 16), dim3(256), 0, stream>>>(attb, wob, out, D_, D_);
}

// Round 4
// 241.701 us; speedup vs baseline: 1.3250x; 1.0459x over previous
//
#include <hip/hip_runtime.h>
#include <stdint.h>

#define B_ 2
#define S_ 2048
#define D_ 2048
#define NH 16
#define NKV 4
#define HD_ 128

typedef unsigned short u16;
typedef unsigned int u32;
typedef __attribute__((ext_vector_type(8))) __bf16 bf16x8;
typedef __attribute__((ext_vector_type(4))) float f32x4;
typedef __attribute__((ext_vector_type(16))) float f32x16;
typedef __attribute__((ext_vector_type(4))) unsigned int u32x4;
typedef __attribute__((ext_vector_type(8))) unsigned short ushort8v;

__device__ __forceinline__ u16 f2bf(float f) {
  u32 u = __builtin_bit_cast(u32, f);
  u32 r = (u + 0x7FFFu + ((u >> 16) & 1u)) >> 16;  // RNE
  return (u16)r;
}
__device__ __forceinline__ float bf2f(u16 h) {
  return __builtin_bit_cast(float, ((u32)h) << 16);
}
__device__ __forceinline__ u32 cvtpk(float lo, float hi) {
  u32 r;
  asm("v_cvt_pk_bf16_f32 %0, %1, %2" : "=v"(r) : "v"(lo), "v"(hi));
  return r;
}
__device__ __forceinline__ f32x16 zero16() {
  f32x16 v;
#pragma unroll
  for (int i = 0; i < 16; ++i) v[i] = 0.f;
  return v;
}

__device__ __forceinline__ void gld_lds16(const void* g, void* l) {
  __builtin_amdgcn_global_load_lds(
      (const __attribute__((address_space(1))) void*)g,
      (__attribute__((address_space(3))) void*)l, 16, 0, 0);
}

// ---------------- fp32 -> bf16 convert ----------------
__global__ __launch_bounds__(256) void k_f2b(const float* __restrict__ src,
                                             u16* __restrict__ dst, int n8) {
  int i = blockIdx.x * 256 + threadIdx.x;
  if (i >= n8) return;
  const float4* s = (const float4*)src + 2 * (size_t)i;
  float4 a = s[0], b = s[1];
  ushort8v o;
  o[0] = f2bf(a.x); o[1] = f2bf(a.y); o[2] = f2bf(a.z); o[3] = f2bf(a.w);
  o[4] = f2bf(b.x); o[5] = f2bf(b.y); o[6] = f2bf(b.z); o[7] = f2bf(b.w);
  *((ushort8v*)dst + i) = o;
}

// ---------------- GEMM: C[M,N] = A[M,K] * W[N,K]^T (bf16 in, fp32 acc) -------
__device__ __forceinline__ void cstore(float* C, size_t i, float v) { C[i] = v; }
__device__ __forceinline__ void cstore(u16* C, size_t i, float v) { C[i] = f2bf(v); }

template <typename OT>
__device__ __forceinline__ void gemm_core(char* lds, const u16* __restrict__ A,
                                          const u16* __restrict__ W, OT* __restrict__ C,
                                          int N, int K, int bx, int by) {
  char* ldsA = lds;
  char* ldsB = lds + 16384;
  const int tid = threadIdx.x;
  const int lane = tid & 63;
  const int wave = tid >> 6;
  const int m0 = bx * 128, n0 = by * 128;
  const int wm = (wave >> 1) * 64, wn = (wave & 1) * 64;
  f32x4 acc[4][4];
#pragma unroll
  for (int i = 0; i < 4; ++i)
#pragma unroll
    for (int j = 0; j < 4; ++j) acc[i][j] = f32x4{0.f, 0.f, 0.f, 0.f};
  const size_t Kb2 = (size_t)K * 2;
  int rowS[4], colS[4];
#pragma unroll
  for (int j = 0; j < 4; ++j) {
    int plin = j * 4096 + tid * 16;
    int o = plin ^ (((plin >> 7) & 7) << 4);
    rowS[j] = o >> 7;
    colS[j] = o & 127;
  }
  for (int kt = 0; kt < K; kt += 64) {
#pragma unroll
    for (int j = 0; j < 4; ++j) {
      gld_lds16((const char*)A + (size_t)(m0 + rowS[j]) * Kb2 + (size_t)kt * 2 + colS[j],
                ldsA + j * 4096 + wave * 1024);
      gld_lds16((const char*)W + (size_t)(n0 + rowS[j]) * Kb2 + (size_t)kt * 2 + colS[j],
                ldsB + j * 4096 + wave * 1024);
    }
    __syncthreads();
#pragma unroll
    for (int kk = 0; kk < 2; ++kk) {
      const int colb = kk * 64 + ((lane >> 4) << 4);
      bf16x8 af[4], bfv[4];
#pragma unroll
      for (int mi = 0; mi < 4; ++mi) {
        int row = wm + mi * 16 + (lane & 15);
        af[mi] = *(const bf16x8*)(ldsA + (row << 7) + (colb ^ ((row & 7) << 4)));
      }
#pragma unroll
      for (int ni = 0; ni < 4; ++ni) {
        int row = wn + ni * 16 + (lane & 15);
        bfv[ni] = *(const bf16x8*)(ldsB + (row << 7) + (colb ^ ((row & 7) << 4)));
      }
#pragma unroll
      for (int mi = 0; mi < 4; ++mi)
#pragma unroll
        for (int ni = 0; ni < 4; ++ni)
          acc[mi][ni] = __builtin_amdgcn_mfma_f32_16x16x32_bf16(af[mi], bfv[ni], acc[mi][ni], 0, 0, 0);
    }
    __syncthreads();
  }
#pragma unroll
  for (int mi = 0; mi < 4; ++mi)
#pragma unroll
    for (int ni = 0; ni < 4; ++ni) {
      const int n = n0 + wn + ni * 16 + (lane & 15);
#pragma unroll
      for (int r = 0; r < 4; ++r) {
        const int m = m0 + wm + mi * 16 + ((lane >> 4) << 2) + r;
        cstore(C, (size_t)m * N + n, acc[mi][ni][r]);
      }
    }
}

__global__ __launch_bounds__(256) void k_gemm_bf(const u16* __restrict__ A,
    const u16* __restrict__ W, u16* __restrict__ C, int N, int K) {
  __shared__ char lds[32768];
  gemm_core(lds, A, W, C, N, K, blockIdx.x, blockIdx.y);
}

__global__ __launch_bounds__(256) void k_gemm_out(const u16* __restrict__ A,
    const u16* __restrict__ W, float* __restrict__ C, int N, int K) {
  __shared__ char lds[32768];
  gemm_core(lds, A, W, C, N, K, blockIdx.x, blockIdx.y);
}

// ---------------- RoPE + relayout: fused-QKV src (row stride rs) ------------
// smul: extra scalar folded into output (Q gets 1/sqrt(HD) here).
__global__ __launch_bounds__(256) void k_rope(const u16* __restrict__ src,
    u16* __restrict__ dst, const float* __restrict__ fc, const float* __restrict__ fs,
    int nh, int lognh, int dorope, int total, int rs, int coloff, float smul) {
  int idx = blockIdx.x * 256 + threadIdx.x;
  if (idx >= total) return;
  const int q4 = idx & 15;
  const int rest = idx >> 4;
  const int hidx = rest & (nh - 1);
  const int t = rest >> lognh;
  const int b = t >> 11, s = t & 2047;
  ushort8v ev = *(const ushort8v*)(src + (size_t)t * rs + coloff + hidx * HD_ + q4 * 8);
  float e[8];
#pragma unroll
  for (int j = 0; j < 8; ++j) e[j] = bf2f(ev[j]);
  float o[8];
  if (dorope) {
    float4 c4 = *(const float4*)(fc + s * 64 + q4 * 4);
    float4 s4 = *(const float4*)(fs + s * 64 + q4 * 4);
    float cc[4] = {c4.x, c4.y, c4.z, c4.w};
    float ss[4] = {s4.x, s4.y, s4.z, s4.w};
#pragma unroll
    for (int j = 0; j < 4; ++j) {
      o[2 * j]     = (e[2 * j] * cc[j] - e[2 * j + 1] * ss[j]) * smul;
      o[2 * j + 1] = (e[2 * j] * ss[j] + e[2 * j + 1] * cc[j]) * smul;
    }
  } else {
#pragma unroll
    for (int j = 0; j < 8; ++j) o[j] = e[j] * smul;
  }
  ushort8v w;
#pragma unroll
  for (int j = 0; j < 8; ++j) w[j] = f2bf(o[j]);
  *(ushort8v*)(dst + (((size_t)(b * nh + hidx)) * S_ + s) * HD_ + q4 * 8) = w;
}

// ---------------- causal GQA flash attention (dbuf + balanced dispatch) -----
// 4 waves x 32 q rows; KVBLK=64; swapped QK^T, in-reg softmax (cvt_pk+shfl),
// defer-max. Q pre-scaled by 1/sqrt(HD) in k_rope. Dispatch pairing: z<8 ->
// qtb=15-z (heavy), z>=8 -> qtb=z-8 (light); blocks c & c+256 share a CU
// under round-robin dispatch => ~36 tile-iters per CU, constant.
__global__ __launch_bounds__(256, 2) void k_attn(const u16* __restrict__ Q,
    const u16* __restrict__ Kt, const u16* __restrict__ V, u16* __restrict__ O) {
  __shared__ char kls[2][16384];   // K tile [64][256B], XOR-swizzled
  __shared__ char vls[2][16384];   // V^T tile [128 hd][128B kv], XOR-swizzled
  const int h = blockIdx.x, b = blockIdx.y;
  const int z = blockIdx.z;
  const int qtb = (z < 8) ? (15 - z) : (z - 8);  // heavy+light pairing
  const int tid = threadIdx.x, lane = tid & 63, wave = tid >> 6;
  const int ql = lane & 31, g = lane >> 5;
  const int kvh = h >> 2;
  const u16* Qb = Q + ((size_t)(b * NH + h)) * S_ * HD_;
  const u16* Kb = Kt + ((size_t)(b * NKV + kvh)) * S_ * HD_;
  const u16* Vb = V + ((size_t)(b * NKV + kvh)) * S_ * HD_;
  const int q0 = qtb * 128, qw0 = q0 + wave * 32;
  const int qme = qw0 + ql;
  int kRowS[4], kColS[4];
#pragma unroll
  for (int j = 0; j < 4; ++j) {
    int plin = j * 4096 + tid * 16;
    int o = plin ^ (((plin >> 8) & 7) << 4);
    kRowS[j] = o >> 8;
    kColS[j] = o & 255;
  }
  const int kp = tid & 31, hb = (tid >> 5) * 16;
  bf16x8 qf[8];
#pragma unroll
  for (int kk = 0; kk < 8; ++kk)
    qf[kk] = *(const bf16x8*)(Qb + (size_t)qme * HD_ + kk * 16 + g * 8);
  f32x16 oacc[4];
#pragma unroll
  for (int th = 0; th < 4; ++th) oacc[th] = zero16();
  float mrun = -1e30f, lrun = 0.0f;
  const int nt = 2 * qtb + 2;

  // ---- prologue: fully stage tile 0 ----
#pragma unroll
  for (int j = 0; j < 4; ++j)
    gld_lds16((const char*)Kb + (size_t)kRowS[j] * 256 + kColS[j],
              &kls[0][0] + j * 4096 + wave * 1024);
  {
    const u16* vp = Vb + (size_t)(2 * kp) * HD_ + hb;
    const u32* r0 = (const u32*)vp;
    const u32* r1 = (const u32*)(vp + HD_);
#pragma unroll
    for (int wd = 0; wd < 8; ++wd) {
      u32 v0 = r0[wd], v1 = r1[wd];
      u32 lo = (v0 & 0xFFFFu) | (v1 << 16);
      u32 hi = (v0 >> 16) | (v1 & 0xFFFF0000u);
      int hd0 = hb + 2 * wd, hd1 = hd0 + 1;
      *(u32*)(&vls[0][0] + hd0 * 128 + ((4 * kp) ^ ((hd0 & 7) << 4))) = lo;
      *(u32*)(&vls[0][0] + hd1 * 128 + ((4 * kp) ^ ((hd1 & 7) << 4))) = hi;
    }
  }
  __syncthreads();

  int cur = 0;
  for (int t = 0; t < nt; ++t) {
    const int kv0 = t * 64;
    const bool haveNext = (t + 1 < nt);
    u32 vr0[8], vr1[8];
    if (haveNext) {
      const int kvn = kv0 + 64;
#pragma unroll
      for (int j = 0; j < 4; ++j)
        gld_lds16((const char*)Kb + (size_t)(kvn + kRowS[j]) * 256 + kColS[j],
                  &kls[cur ^ 1][0] + j * 4096 + wave * 1024);
      const u16* vp = Vb + (size_t)(kvn + 2 * kp) * HD_ + hb;
      const u32* r0 = (const u32*)vp;
      const u32* r1 = (const u32*)(vp + HD_);
#pragma unroll
      for (int wd = 0; wd < 8; ++wd) { vr0[wd] = r0[wd]; vr1[wd] = r1[wd]; }
    }
    if (kv0 <= qw0 + 31) {
      const char* kcur = &kls[cur][0];
      const char* vcur = &vls[cur][0];
      f32x16 c0 = zero16(), c1 = zero16();
      __builtin_amdgcn_s_setprio(1);
#pragma unroll
      for (int kk = 0; kk < 8; ++kk) {
        const int sw = (kk * 32 + 16 * g) ^ ((ql & 7) << 4);
        bf16x8 kf0 = *(const bf16x8*)(kcur + (ql << 8) + sw);
        bf16x8 kf1 = *(const bf16x8*)(kcur + ((32 + ql) << 8) + sw);
        c0 = __builtin_amdgcn_mfma_f32_32x32x16_bf16(kf0, qf[kk], c0, 0, 0, 0);
        c1 = __builtin_amdgcn_mfma_f32_32x32x16_bf16(kf1, qf[kk], c1, 0, 0, 0);
      }
      __builtin_amdgcn_s_setprio(0);
      const bool diag = (kv0 + 63 > qw0);
      float mt = -1e30f;
      if (diag) {
#pragma unroll
        for (int r = 0; r < 16; ++r) {
          float s0 = c0[r];
          float s1 = c1[r];
          int kb = kv0 + (r & 3) + ((r >> 2) << 3) + 4 * g;
          if (kb > qme) s0 = -1e30f;
          if (kb + 32 > qme) s1 = -1e30f;
          c0[r] = s0; c1[r] = s1;
          mt = fmaxf(mt, fmaxf(s0, s1));
        }
      } else {
#pragma unroll
        for (int r = 0; r < 16; ++r)
          mt = fmaxf(mt, fmaxf(c0[r], c1[r]));
      }
      mt = fmaxf(mt, __shfl_xor(mt, 32));
      if (!__all(mt <= mrun + 8.0f)) {
        float mnew = fmaxf(mrun, mt);
        float alpha = __expf(mrun - mnew);
        lrun *= alpha;
        mrun = mnew;
#pragma unroll
        for (int r = 0; r < 16; ++r) {
          float av = __shfl(alpha, 36 * g + (r & 3) + ((r >> 2) << 3));
          oacc[0][r] *= av; oacc[1][r] *= av;
          oacc[2][r] *= av; oacc[3][r] *= av;
        }
      }
      float lt = 0.0f;
#pragma unroll
      for (int r = 0; r < 16; ++r) {
        float p0 = __expf(c0[r] - mrun);
        float p1 = __expf(c1[r] - mrun);
        c0[r] = p0; c1[r] = p1;
        lt += p0 + p1;
      }
      lt += __shfl_xor(lt, 32);
      lrun += lt;
      u32 paw[4][4];
#pragma unroll
      for (int a = 0; a < 2; ++a) {
        {
          u32 X = cvtpk(c0[8 * a + 0], c0[8 * a + 1]);
          u32 Y = cvtpk(c0[8 * a + 2], c0[8 * a + 3]);
          u32 Z = cvtpk(c0[8 * a + 4], c0[8 * a + 5]);
          u32 W = cvtpk(c0[8 * a + 6], c0[8 * a + 7]);
          u32 S1 = g ? X : Z, S2 = g ? Y : W;
          u32 R1 = (u32)__shfl_xor((int)S1, 32), R2 = (u32)__shfl_xor((int)S2, 32);
          paw[a][0] = g ? R1 : X; paw[a][1] = g ? R2 : Y;
          paw[a][2] = g ? Z : R1; paw[a][3] = g ? W : R2;
        }
        {
          u32 X = cvtpk(c1[8 * a + 0], c1[8 * a + 1]);
          u32 Y = cvtpk(c1[8 * a + 2], c1[8 * a + 3]);
          u32 Z = cvtpk(c1[8 * a + 4], c1[8 * a + 5]);
          u32 W = cvtpk(c1[8 * a + 6], c1[8 * a + 7]);
          u32 S1 = g ? X : Z, S2 = g ? Y : W;
          u32 R1 = (u32)__shfl_xor((int)S1, 32), R2 = (u32)__shfl_xor((int)S2, 32);
          paw[2 + a][0] = g ? R1 : X; paw[2 + a][1] = g ? R2 : Y;
          paw[2 + a][2] = g ? Z : R1; paw[2 + a][3] = g ? W : R2;
        }
      }
      __builtin_amdgcn_s_setprio(1);
#pragma unroll
      for (int ks = 0; ks < 4; ++ks) {
        bf16x8 pf = __builtin_bit_cast(bf16x8,
            u32x4{paw[ks][0], paw[ks][1], paw[ks][2], paw[ks][3]});
        const int cb = (32 * ks + 16 * g) ^ ((ql & 7) << 4);
#pragma unroll
        for (int th = 0; th < 4; ++th) {
          bf16x8 vf = *(const bf16x8*)(vcur + ((th * 32 + ql) << 7) + cb);
          oacc[th] = __builtin_amdgcn_mfma_f32_32x32x16_bf16(pf, vf, oacc[th], 0, 0, 0);
        }
      }
      __builtin_amdgcn_s_setprio(0);
    }
    if (haveNext) {
      char* vn = &vls[cur ^ 1][0];
#pragma unroll
      for (int wd = 0; wd < 8; ++wd) {
        u32 v0 = vr0[wd], v1 = vr1[wd];
        u32 lo = (v0 & 0xFFFFu) | (v1 << 16);
        u32 hi = (v0 >> 16) | (v1 & 0xFFFF0000u);
        int hd0 = hb + 2 * wd, hd1 = hd0 + 1;
        *(u32*)(vn + hd0 * 128 + ((4 * kp) ^ ((hd0 & 7) << 4))) = lo;
        *(u32*)(vn + hd1 * 128 + ((4 * kp) ^ ((hd1 & 7) << 4))) = hi;
      }
    }
    __syncthreads();
    cur ^= 1;
  }
#pragma unroll
  for (int r = 0; r < 16; ++r) {
    float lr = __shfl(lrun, 36 * g + (r & 3) + ((r >> 2) << 3));
    float li = 1.0f / lr;
    int q = qw0 + (r & 3) + ((r >> 2) << 3) + 4 * g;
    size_t rowo = (size_t)(b * S_ + q) * D_ + h * HD_ + ql;
#pragma unroll
    for (int th = 0; th < 4; ++th)
      O[rowo + 32 * th] = f2bf(oacc[th][r] * li);
  }
}

// ---------------- launcher ----------------
extern "C" void kernel_launch(void* const* d_in, const int* in_sizes, int n_in,
                              void* d_out, int out_size, void* d_ws, size_t ws_size,
                              hipStream_t stream) {
  const float* x  = (const float*)d_in[0];
  const float* wq = (const float*)d_in[1];
  const float* wk = (const float*)d_in[2];
  const float* wv = (const float*)d_in[3];
  const float* wo = (const float*)d_in[4];
  const float* fc = (const float*)d_in[5];
  const float* fs = (const float*)d_in[6];
  float* out = (float*)d_out;
  char* ws = (char*)d_ws;
  const size_t MB = 1ull << 20;
  u16* xb    = (u16*)(ws);
  u16* wqkv  = (u16*)(ws + 16 * MB);           // [3072][2048] fused q|k|v
  u16* wob   = (u16*)(ws + 28 * MB);
  u16* qkvbf = (u16*)(ws + 36 * MB);           // [4096][3072]
  u16* Qb    = (u16*)(ws);                     // alias xb
  u16* Kb    = (u16*)(ws + 16 * MB);           // alias wqkv
  u16* Vb    = (u16*)(ws + 20 * MB);
  u16* attb  = (u16*)(ws + 36 * MB);           // alias qkvbf

  auto cv = [&](const float* s, u16* d, int n) {
    int n8 = n / 8;
    k_f2b<<<dim3((n8 + 255) / 256), dim3(256), 0, stream>>>(s, d, n8);
  };
  cv(x,  xb,   B_ * S_ * D_);
  cv(wq, wqkv,            D_ * D_);
  cv(wk, wqkv + 2048*2048, 512 * D_);
  cv(wv, wqkv + 2560*2048, 512 * D_);
  cv(wo, wob,  D_ * D_);

  k_gemm_bf<<<dim3(32, 24), dim3(256), 0, stream>>>(xb, wqkv, qkvbf, 3072, D_);

  const float qscale = 0.08838834764831845f;  // 1/sqrt(128), folded into Q
  k_rope<<<dim3(4096), dim3(256), 0, stream>>>(qkvbf, Qb, fc, fs, 16, 4, 1,
                                               B_ * S_ * 16 * 16, 3072, 0, qscale);
  k_rope<<<dim3(1024), dim3(256), 0, stream>>>(qkvbf, Kb, fc, fs, 4, 2, 1,
                                               B_ * S_ * 4 * 16, 3072, 2048, 1.0f);
  k_rope<<<dim3(1024), dim3(256), 0, stream>>>(qkvbf, Vb, fc, fs, 4, 2, 0,
                                               B_ * S_ * 4 * 16, 3072, 2560, 1.0f);

  k_attn<<<dim3(NH, B_, 16), dim3(256), 0, stream>>>(Qb, Kb, Vb, attb);

  k_gemm_out<<<dim3(32, 16), dim3(256), 0, stream>>>(attb, wob, out, D_, D_);
}